// Round 3
// baseline (350.717 us; speedup 1.0000x reference)
//
#include <hip/hip_runtime.h>
#include <math.h>

static constexpr int Bn = 8;
static constexpr int Cn = 256;
static constexpr int Sn = 16384;   // 128*128

typedef __bf16 bf16x4 __attribute__((ext_vector_type(4)));
typedef __bf16 bf16x8 __attribute__((ext_vector_type(8)));
typedef float  f32x4  __attribute__((ext_vector_type(4)));

// ---------------- shared LDS layout helpers ----------------
// Tile buffer: 128 rows x 32 bf16 (one K-chunk), zero pad, XOR chunk swizzle.
// Row = 64 B = 4 chunks of 16 B. Data chunk c of row r lives at slot c^(r&3).
// -> frag reads (b128) 8 accesses/bank (floor), staging writes (b64) 4/bank (floor).
__device__ __forceinline__ void split_store(__bf16* __restrict__ Hi, __bf16* __restrict__ Lo,
                                            int row, int kq, float4 v) {
  __bf16 h0 = (__bf16)v.x, h1 = (__bf16)v.y, h2 = (__bf16)v.z, h3 = (__bf16)v.w;
  int off = row * 32 + (((kq >> 1) ^ (row & 3)) << 3) + ((kq & 1) << 2);
  *(bf16x4*)&Hi[off] = (bf16x4){h0, h1, h2, h3};
  *(bf16x4*)&Lo[off] = (bf16x4){(__bf16)(v.x - (float)h0), (__bf16)(v.y - (float)h1),
                                (__bf16)(v.z - (float)h2), (__bf16)(v.w - (float)h3)};
}

__device__ __forceinline__ bf16x8 frag_ld(const __bf16* __restrict__ P, int row, int quad) {
  return *(const bf16x8*)&P[row * 32 + ((quad ^ (row & 3)) << 3)];
}

// ---------------- Kernel 1: partial Gram (energy) via split-bf16 MFMA -------
// energy[b][c][d] = sum_s v[b,c,s] * v[b,d,s];  symmetric -> compute 3 tiles:
// tsel 0:(0,0) diag, 1:(1,1) diag, 2:(0,1) + mirror into (1,0).
// Diagonal tiles stage rows once (A buffer serves both operands).
static constexpr int TILE   = 128;
static constexpr int KSPLIT = 16;
static constexpr int KSLICE = Sn / KSPLIT;  // 1024
static constexpr int KB     = 32;

__global__ __launch_bounds__(256, 2) void gram_kernel(const float* __restrict__ x,
                                                      float* __restrict__ energy) {
  const int b    = blockIdx.z;
  const int tsel = blockIdx.y;            // 0,1,2
  const int kk   = blockIdx.x;            // k-slice
  const int ti   = (tsel == 1) ? 1 : 0;
  const int tj   = (tsel == 0) ? 0 : 1;
  const bool diag = (tsel < 2);

  const float* vb    = x + (size_t)b * Cn * Sn;
  const float* Abase = vb + (size_t)(ti * TILE) * Sn + kk * KSLICE;
  const float* Bbase = vb + (size_t)(tj * TILE) * Sn + kk * KSLICE;

  __shared__ __align__(16) __bf16 Ah[TILE * 32];
  __shared__ __align__(16) __bf16 Al[TILE * 32];
  __shared__ __align__(16) __bf16 Bh[TILE * 32];
  __shared__ __align__(16) __bf16 Bl[TILE * 32];

  const int t    = threadIdx.x;           // 0..255
  const int lane = t & 63;
  const int wv   = t >> 6;
  const int wr   = wv >> 1;               // wave row (c)
  const int wc   = wv & 1;                // wave col (d)
  const int ln   = lane & 15;
  const int quad = lane >> 4;

  const int srow = t >> 3;                // staging row base 0..31
  const int skq  = t & 7;                 // float4 index within chunk

  float4 areg[4], breg[4];

#pragma unroll
  for (int it = 0; it < 4; it++)
    areg[it] = *(const float4*)(Abase + (size_t)(srow + it * 32) * Sn + skq * 4);
  if (!diag) {
#pragma unroll
    for (int it = 0; it < 4; it++)
      breg[it] = *(const float4*)(Bbase + (size_t)(srow + it * 32) * Sn + skq * 4);
  }

  f32x4 acc[4][4];
#pragma unroll
  for (int i = 0; i < 4; i++)
#pragma unroll
    for (int j = 0; j < 4; j++) acc[i][j] = (f32x4){0.f, 0.f, 0.f, 0.f};

  for (int kc = 0; kc < KSLICE; kc += KB) {
    // convert staged regs -> (hi,lo) bf16 into swizzled LDS
#pragma unroll
    for (int it = 0; it < 4; it++) split_store(Ah, Al, srow + it * 32, skq, areg[it]);
    if (!diag) {
#pragma unroll
      for (int it = 0; it < 4; it++) split_store(Bh, Bl, srow + it * 32, skq, breg[it]);
    }
    __syncthreads();

    const __bf16* PH = diag ? Ah : Bh;
    const __bf16* PL = diag ? Al : Bl;

    bf16x8 fah[4], fal[4];
#pragma unroll
    for (int i = 0; i < 4; i++) {
      int ar = wr * 64 + i * 16 + ln;
      fah[i] = frag_ld(Ah, ar, quad);
      fal[i] = frag_ld(Al, ar, quad);
    }

    // issue next chunk's global loads now; latency hides under MFMA + barrier
    if (kc + KB < KSLICE) {
#pragma unroll
      for (int it = 0; it < 4; it++)
        areg[it] = *(const float4*)(Abase + (size_t)(srow + it * 32) * Sn + (kc + KB) + skq * 4);
      if (!diag) {
#pragma unroll
        for (int it = 0; it < 4; it++)
          breg[it] = *(const float4*)(Bbase + (size_t)(srow + it * 32) * Sn + (kc + KB) + skq * 4);
      }
    }

#pragma unroll
    for (int j = 0; j < 4; j++) {
      int br = wc * 64 + j * 16 + ln;
      bf16x8 fbh = frag_ld(PH, br, quad);
      bf16x8 fbl = frag_ld(PL, br, quad);
#pragma unroll
      for (int i = 0; i < 4; i++) {
        acc[i][j] = __builtin_amdgcn_mfma_f32_16x16x32_bf16(fah[i], fbh, acc[i][j], 0, 0, 0);
        acc[i][j] = __builtin_amdgcn_mfma_f32_16x16x32_bf16(fah[i], fbl, acc[i][j], 0, 0, 0);
        acc[i][j] = __builtin_amdgcn_mfma_f32_16x16x32_bf16(fal[i], fbh, acc[i][j], 0, 0, 0);
      }
    }
    __syncthreads();
  }

  // epilogue: C/D layout col=lane&15, row=quad*4+reg; mirror for off-diag tile
  float* E = energy + (size_t)b * Cn * Cn;
#pragma unroll
  for (int i = 0; i < 4; i++)
#pragma unroll
    for (int j = 0; j < 4; j++) {
      int c0 = ti * TILE + wr * 64 + i * 16 + quad * 4;
      int d  = tj * TILE + wc * 64 + j * 16 + ln;
#pragma unroll
      for (int r = 0; r < 4; r++) {
        float v = acc[i][j][r];
        atomicAdd(&E[(size_t)(c0 + r) * Cn + d], v);
        if (tsel == 2) atomicAdd(&E[(size_t)d * Cn + (c0 + r)], v);
      }
    }
}

// ---------------- Kernel 2: softmax, wave per row, no barriers ----------------
// softmax(max_d(e) - e) over d  ==  exp(e_min - e_d) / sum  (row max cancels)
__global__ __launch_bounds__(256) void softmax_kernel(float* __restrict__ energy) {
  const int wv   = threadIdx.x >> 6;
  const int lane = threadIdx.x & 63;
  const int row  = blockIdx.x * 4 + wv;

  float4 e = *(const float4*)&energy[(size_t)row * Cn + lane * 4];
  float m = fminf(fminf(e.x, e.y), fminf(e.z, e.w));
#pragma unroll
  for (int off = 32; off > 0; off >>= 1) m = fminf(m, __shfl_xor(m, off));

  float4 p;
  p.x = expf(m - e.x); p.y = expf(m - e.y);
  p.z = expf(m - e.z); p.w = expf(m - e.w);
  float s = p.x + p.y + p.z + p.w;
#pragma unroll
  for (int off = 32; off > 0; off >>= 1) s += __shfl_xor(s, off);

  float inv = 1.f / s;
  p.x *= inv; p.y *= inv; p.z *= inv; p.w *= inv;
  *(float4*)&energy[(size_t)row * Cn + lane * 4] = p;
}

// ---------------- Kernel 3: y = w @ v via split-bf16 MFMA, out = alpha*y + x -
// A = w[b] (256x256 fp32, k contiguous). B = v[b] (k slow axis -> transpose via
// per-lane k-column scalar loads, vector LDS writes). Pipelined like gram.
__global__ __launch_bounds__(256, 2) void ygemm_mfma_kernel(const float* __restrict__ w,
                                                            const float* __restrict__ x,
                                                            const float* __restrict__ alpha,
                                                            float* __restrict__ out) {
  const int b  = blockIdx.z;
  const int m0 = blockIdx.y * 128;        // output row tile (c)
  const int s0 = blockIdx.x * 128;        // output col tile (s)

  const float* Wb = w + ((size_t)b * Cn + m0) * Cn;
  const float* Vb = x + (size_t)b * Cn * Sn;

  __shared__ __align__(16) __bf16 Ah[128 * 32];
  __shared__ __align__(16) __bf16 Al[128 * 32];
  __shared__ __align__(16) __bf16 Bh[128 * 32];   // transposed: [s][k]
  __shared__ __align__(16) __bf16 Bl[128 * 32];

  const int t    = threadIdx.x;
  const int lane = t & 63;
  const int wv   = t >> 6;
  const int wr   = wv >> 1;               // wave row (m)
  const int wc   = wv & 1;                // wave col (s)
  const int ln   = lane & 15;
  const int quad = lane >> 4;

  const int srow = t >> 3;                // staging row base 0..31 (A: m row, B: s row)
  const int skq  = t & 7;                 // chunk-quad (k group of 4)

  float4 areg[4];
  float  breg[16];

#pragma unroll
  for (int it = 0; it < 4; it++)
    areg[it] = *(const float4*)(Wb + (size_t)(srow + it * 32) * Cn + skq * 4);
#pragma unroll
  for (int it = 0; it < 4; it++) {
    const float* col = Vb + (size_t)(skq * 4) * Sn + s0 + srow + it * 32;
    breg[it * 4 + 0] = col[0];
    breg[it * 4 + 1] = col[(size_t)Sn];
    breg[it * 4 + 2] = col[(size_t)2 * Sn];
    breg[it * 4 + 3] = col[(size_t)3 * Sn];
  }

  f32x4 acc[4][4];
#pragma unroll
  for (int i = 0; i < 4; i++)
#pragma unroll
    for (int j = 0; j < 4; j++) acc[i][j] = (f32x4){0.f, 0.f, 0.f, 0.f};

  for (int kc = 0; kc < Cn; kc += KB) {
#pragma unroll
    for (int it = 0; it < 4; it++) split_store(Ah, Al, srow + it * 32, skq, areg[it]);
#pragma unroll
    for (int it = 0; it < 4; it++) {
      float4 bv = make_float4(breg[it * 4 + 0], breg[it * 4 + 1],
                              breg[it * 4 + 2], breg[it * 4 + 3]);
      split_store(Bh, Bl, srow + it * 32, skq, bv);
    }
    __syncthreads();

    bf16x8 fah[4], fal[4];
#pragma unroll
    for (int i = 0; i < 4; i++) {
      int ar = wr * 64 + i * 16 + ln;
      fah[i] = frag_ld(Ah, ar, quad);
      fal[i] = frag_ld(Al, ar, quad);
    }

    if (kc + KB < Cn) {
#pragma unroll
      for (int it = 0; it < 4; it++)
        areg[it] = *(const float4*)(Wb + (size_t)(srow + it * 32) * Cn + (kc + KB) + skq * 4);
#pragma unroll
      for (int it = 0; it < 4; it++) {
        const float* col = Vb + (size_t)((kc + KB) + skq * 4) * Sn + s0 + srow + it * 32;
        breg[it * 4 + 0] = col[0];
        breg[it * 4 + 1] = col[(size_t)Sn];
        breg[it * 4 + 2] = col[(size_t)2 * Sn];
        breg[it * 4 + 3] = col[(size_t)3 * Sn];
      }
    }

#pragma unroll
    for (int j = 0; j < 4; j++) {
      int br = wc * 64 + j * 16 + ln;
      bf16x8 fbh = frag_ld(Bh, br, quad);
      bf16x8 fbl = frag_ld(Bl, br, quad);
#pragma unroll
      for (int i = 0; i < 4; i++) {
        acc[i][j] = __builtin_amdgcn_mfma_f32_16x16x32_bf16(fah[i], fbh, acc[i][j], 0, 0, 0);
        acc[i][j] = __builtin_amdgcn_mfma_f32_16x16x32_bf16(fah[i], fbl, acc[i][j], 0, 0, 0);
        acc[i][j] = __builtin_amdgcn_mfma_f32_16x16x32_bf16(fal[i], fbh, acc[i][j], 0, 0, 0);
      }
    }
    __syncthreads();
  }

  // epilogue: fuse residual + alpha
  const float al = alpha[0];
#pragma unroll
  for (int i = 0; i < 4; i++)
#pragma unroll
    for (int j = 0; j < 4; j++) {
      int c = m0 + wr * 64 + i * 16 + quad * 4;
      int s = s0 + wc * 64 + j * 16 + ln;
      const float* xr = x   + ((size_t)b * Cn + c) * Sn + s;
      float*       op = out + ((size_t)b * Cn + c) * Sn + s;
#pragma unroll
      for (int r = 0; r < 4; r++)
        op[(size_t)r * Sn] = al * acc[i][j][r] + xr[(size_t)r * Sn];
    }
}

extern "C" void kernel_launch(void* const* d_in, const int* in_sizes, int n_in,
                              void* d_out, int out_size, void* d_ws, size_t ws_size,
                              hipStream_t stream) {
  const float* x     = (const float*)d_in[0];
  const float* alpha = (const float*)d_in[1];
  float*       out   = (float*)d_out;
  float*       energy = (float*)d_ws;          // B*C*C fp32 = 2 MB; becomes w in-place

  const size_t energy_bytes = (size_t)Bn * Cn * Cn * sizeof(float);
  hipMemsetAsync(energy, 0, energy_bytes, stream);

  dim3 g1(KSPLIT, 3, Bn);                      // 16 x 3 x 8 = 384 blocks (symmetric)
  gram_kernel<<<g1, 256, 0, stream>>>(x, energy);

  softmax_kernel<<<(Bn * Cn) / 4, 256, 0, stream>>>(energy);

  dim3 g3(Sn / 128, Cn / 128, Bn);             // 128 x 2 x 8 = 2048 blocks
  ygemm_mfma_kernel<<<g3, 256, 0, stream>>>(energy, x, alpha, out);
}